// Round 4
// baseline (445.929 us; speedup 1.0000x reference)
//
#include <hip/hip_runtime.h>

typedef unsigned short u16;
typedef unsigned int   u32;
typedef __attribute__((ext_vector_type(4)))  u16   us4;
typedef __attribute__((ext_vector_type(8)))  u16   us8;
typedef __attribute__((ext_vector_type(8)))  short s8v;
typedef __attribute__((ext_vector_type(16))) float f32x16;

#define L_   2048
#define D_   512
#define H_   8
#define PE_  2097152ull      // B*L*D elements of one fp32 projection array

// ---- ws layout (bytes) ----
//  [0 .. 32MB)   : 8 bf16 mats (QRH,QRL,QIH,QIL,KRH,KRL,KIH,KIL), each [bh][i][64]
//  [32 .. 40MB)  : 2 bf16 mats VTR,VTI, each [bh][dh][2048]  (V transposed)
//  [40 .. 56MB)  : o splits: ORH,ORL,OIH,OIL bf16 [4096][512]
#define MATE    2097152ull   // u16 elems per mat
#define BHE     131072u      // u16 elems per (bh) slice of a mat (2048*64)
#define VT_OFF  33554432ull
#define ORH_OFF 41943040ull
#define ORL_OFF 46137344ull
#define OIH_OFF 50331648ull
#define OIL_OFF 54525952ull

// ---- d_out scratch (bytes from out base; inside attnbuf, dead before attn writes) ----
#define XRH_O 16777216ull
#define XRL_O 20971520ull
#define XIH_O 25165824ull
#define XIL_O 29360128ull

#define MFMA32(a,b,c) __builtin_amdgcn_mfma_f32_32x32x16_bf16(a,b,c,0,0,0)
#define ROWOF(r,hi) (((r)&3) + 8*((r)>>2) + 4*(hi))

__device__ __forceinline__ u16 f2bf(float x){
    u32 u = __float_as_uint(x);
    u += 0x7FFFu + ((u>>16)&1u);
    return (u16)(u>>16);
}
__device__ __forceinline__ float bf2f(u16 h){ return __uint_as_float(((u32)h)<<16); }

// ============================================================
// Prep: split wave_real / wave_imag into bf16 hi/lo mats (d_out scratch)
// ============================================================
__global__ __launch_bounds__(256)
void split_prep_kernel(const float* __restrict__ wr, const float* __restrict__ wi,
                       unsigned char* __restrict__ outb)
{
    const int z = blockIdx.y;
    const float* src = z ? wi : wr;
    u16* hg = (u16*)(outb + (z ? XIH_O : XRH_O));
    u16* lg = (u16*)(outb + (z ? XIL_O : XRL_O));
    const size_t idx4 = ((size_t)blockIdx.x * 256 + threadIdx.x) * 4;
    float4 v = *(const float4*)&src[idx4];
    float vv[4] = { v.x, v.y, v.z, v.w };
    us4 h, l;
    #pragma unroll
    for (int c = 0; c < 4; ++c) {
        u16 hb = f2bf(vv[c]);
        h[c] = hb;
        l[c] = f2bf(vv[c] - bf2f(hb));
    }
    *(us4*)&hg[idx4] = h;
    *(us4*)&lg[idx4] = l;
}

// ============================================================
// Shared LDS fragment helpers (XOR swizzle byte ^= (row&7)<<4, both sides)
// ============================================================
__device__ __forceinline__ s8v ldfrag(const unsigned char* Lp, u32 matOff, u32 row, u32 colb)
{
    return *(const s8v*)(Lp + matOff + row*128u + (colb ^ ((row&7u)<<4)));
}

// reg-staged 64x64 bf16 mat: 2 x us8 per thread
struct regs2 { us8 a, b; };
__device__ __forceinline__ void load_mat_qk(regs2& r, const u16* __restrict__ g,
                                            int rowBase, int ch, int r0)
{
    r.a = *(const us8*)(g + (size_t)(rowBase + r0)*64 + ch*8);
    r.b = *(const us8*)(g + (size_t)(rowBase + 32 + r0)*64 + ch*8);
}
__device__ __forceinline__ void load_mat_vt(regs2& r, const u16* __restrict__ g,
                                            int j0, int ch, int r0)
{
    r.a = *(const us8*)(g + (size_t)(r0)*2048 + j0 + ch*8);
    r.b = *(const us8*)(g + (size_t)(32 + r0)*2048 + j0 + ch*8);
}
__device__ __forceinline__ void write_mat(unsigned char* Lp, u32 off, const regs2& r,
                                          int ch, int r0)
{
    u32 row0 = (u32)r0, row1 = (u32)(32 + r0);
    *(us8*)(Lp + off + row0*128u + (((u32)ch<<4) ^ ((row0&7u)<<4))) = r.a;
    *(us8*)(Lp + off + row1*128u + (((u32)ch<<4) ^ ((row1&7u)<<4))) = r.b;
}

// ============================================================
// MFMA projection: C = X @ W^T + b for 6 combos.  (unchanged)
// ============================================================
__global__ __launch_bounds__(256, 2)
void proj_mfma_kernel(const unsigned char* __restrict__ scr,
                      const float* __restrict__ Wq, const float* __restrict__ Wk,
                      const float* __restrict__ Wv,
                      const float* __restrict__ bq, const float* __restrict__ bk,
                      const float* __restrict__ bv,
                      u16* __restrict__ qk, u16* __restrict__ vt)
{
    const int z = blockIdx.z;
    const u16* Ah_g = (const u16*)(scr + ((z & 1) ? XIH_O : XRH_O));
    const u16* Al_g = (const u16*)(scr + ((z & 1) ? XIL_O : XRL_O));
    const int wsel = z >> 1;
    const float* Wf; const float* bias;
    if (wsel == 0)      { Wf = Wq; bias = bq; }
    else if (wsel == 1) { Wf = Wk; bias = bk; }
    else                { Wf = Wv; bias = bv; }
    const bool four = (wsel < 2);

    const int m0 = blockIdx.x * 128;
    const int n0 = blockIdx.y * 64;

    __shared__ __align__(16) unsigned char L[49152];
    enum : u32 { AH=0, AL=16384, BH=32768, BL=40960 };

    const int tid  = threadIdx.x;
    const int lane = tid & 63;
    const int wid  = tid >> 6;
    const int wr   = wid >> 1, wc = wid & 1;
    const int l31  = lane & 31;
    const int hi   = lane >> 5;
    const u32 rowA0 = (u32)(wr*64 + l31);
    const u32 rowB  = (u32)(wc*32 + l31);

    f32x16 c0, c1;
    #pragma unroll
    for (int r = 0; r < 16; ++r) { c0[r] = 0.f; c1[r] = 0.f; }

    const int ch = tid & 7, r0 = tid >> 3;

    for (int k0 = 0; k0 < 512; k0 += 64) {
        __syncthreads();
        #pragma unroll
        for (int rr = 0; rr < 4; ++rr) {
            u32 row = (u32)(rr*32 + r0);
            u32 dst = row*128u + (((u32)ch<<4) ^ ((row&7u)<<4));
            us8 vh = *(const us8*)(Ah_g + (size_t)(m0 + row)*512 + k0 + ch*8);
            *(us8*)(L + AH + dst) = vh;
            if (four) {
                us8 vl = *(const us8*)(Al_g + (size_t)(m0 + row)*512 + k0 + ch*8);
                *(us8*)(L + AL + dst) = vl;
            }
        }
        #pragma unroll
        for (int rr = 0; rr < 2; ++rr) {
            u32 row = (u32)(rr*32 + r0);
            const float* src = Wf + (size_t)(n0 + row)*512 + k0 + ch*8;
            float4 v0 = *(const float4*)src;
            float4 v1 = *(const float4*)(src + 4);
            float vv[8] = { v0.x,v0.y,v0.z,v0.w, v1.x,v1.y,v1.z,v1.w };
            us8 hv, lv;
            #pragma unroll
            for (int j = 0; j < 8; ++j) {
                u16 hb = f2bf(vv[j]);
                hv[j] = hb;
                lv[j] = f2bf(vv[j] - bf2f(hb));
            }
            u32 dst = row*128u + (((u32)ch<<4) ^ ((row&7u)<<4));
            *(us8*)(L + BH + dst) = hv;
            if (four) *(us8*)(L + BL + dst) = lv;
        }
        __syncthreads();

        #pragma unroll
        for (int ks = 0; ks < 4; ++ks) {
            u32 colb = (u32)(ks*32 + hi*16);
            s8v a0h = ldfrag(L, AH, rowA0,      colb);
            s8v a1h = ldfrag(L, AH, rowA0 + 32, colb);
            s8v bh_ = ldfrag(L, BH, rowB,       colb);
            c0 = MFMA32(a0h, bh_, c0);
            c1 = MFMA32(a1h, bh_, c1);
            if (four) {
                s8v a0l = ldfrag(L, AL, rowA0,      colb);
                s8v a1l = ldfrag(L, AL, rowA0 + 32, colb);
                s8v bl_ = ldfrag(L, BL, rowB,       colb);
                c0 = MFMA32(a0h, bl_, c0); c0 = MFMA32(a0l, bh_, c0); c0 = MFMA32(a0l, bl_, c0);
                c1 = MFMA32(a1h, bl_, c1); c1 = MFMA32(a1l, bh_, c1); c1 = MFMA32(a1l, bl_, c1);
            }
        }
    }

    const int n  = n0 + wc*32 + l31;
    const float bvv = bias[n];
    const int h  = n >> 6, dh = n & 63;

    if (z < 4) {
        u16* hg = qk + (size_t)(2*z)   * MATE;
        u16* lg = qk + (size_t)(2*z+1) * MATE;
        #pragma unroll
        for (int f = 0; f < 2; ++f) {
            const f32x16& c = f ? c1 : c0;
            #pragma unroll
            for (int r = 0; r < 16; ++r) {
                int m  = m0 + wr*64 + 32*f + ROWOF(r, hi);
                int b_ = m >> 11, i = m & 2047;
                size_t idx = (size_t)(b_*8 + h)*BHE + (size_t)i*64 + dh;
                float v = c[r] + bvv;
                u16 hb = f2bf(v);
                hg[idx] = hb;
                lg[idx] = f2bf(v - bf2f(hb));
            }
        }
    } else {
        u16* vg = vt + (size_t)(z & 1) * MATE;
        #pragma unroll
        for (int f = 0; f < 2; ++f) {
            const f32x16& c = f ? c1 : c0;
            #pragma unroll
            for (int g = 0; g < 4; ++g) {
                int mb = m0 + wr*64 + 32*f + 8*g + 4*hi;
                int b_ = mb >> 11, ib = mb & 2047;
                us4 pv;
                #pragma unroll
                for (int j = 0; j < 4; ++j) pv[j] = f2bf(c[4*g + j] + bvv);
                *(us4*)&vg[(size_t)(b_*8 + h)*BHE + (size_t)dh*2048 + ib] = pv;
            }
        }
    }
}

// ============================================================
// MFMA attention, fused normalization.
// sweep1: full 3-term QK, per-lane online (m,l); combine at end.
// sweep2: recompute QK, write NORMALIZED attention + normalized P; PV.
// Q frags hoisted to regs; K/V reg-staged a phase early (T14).
// sweep1: 1 barrier/jt (K double-buffered KA/KB);
// sweep2: 2 barriers/jt (K in KA; V region; P region).  LDS = 64 KB.
// ============================================================
__global__ __launch_bounds__(256, 2)
void attn_mfma_kernel(const u16* __restrict__ qk,
                      const u16* __restrict__ vt,
                      float* __restrict__ attnbuf,
                      u16* __restrict__ orh, u16* __restrict__ orl,
                      u16* __restrict__ oih, u16* __restrict__ oil)
{
    const int bh = blockIdx.x;
    const int i0 = blockIdx.y * 64;
    const int tid  = threadIdx.x;
    const int lane = tid & 63;
    const int wid  = tid >> 6;
    const int wr   = wid >> 1, wc = wid & 1;
    const int l31  = lane & 31;
    const int hi   = lane >> 5;
    const u32 rowA = wr*32 + l31;
    const u32 rowB = wc*32 + l31;
    const int ch = tid & 7, r0 = tid >> 3;

    __shared__ __align__(16) unsigned char L[65536];
    enum : u32 { KA = 0, KB = 32768, VRo = 32768, VIo = 40960, PAC = 49152, PAS = 57344 };

    const u16* qrh = qk + 0*MATE + (size_t)bh*BHE;
    const u16* qrl = qk + 1*MATE + (size_t)bh*BHE;
    const u16* qih = qk + 2*MATE + (size_t)bh*BHE;
    const u16* qil = qk + 3*MATE + (size_t)bh*BHE;
    const u16* krh = qk + 4*MATE + (size_t)bh*BHE;
    const u16* krl = qk + 5*MATE + (size_t)bh*BHE;
    const u16* kih = qk + 6*MATE + (size_t)bh*BHE;
    const u16* kil = qk + 7*MATE + (size_t)bh*BHE;
    const u16* vtr = vt + 0*MATE + (size_t)bh*BHE;
    const u16* vti = vt + 1*MATE + (size_t)bh*BHE;

    // ---- prologue: issue K(0) loads, stage Q -> KB, K(0) -> KA ----
    regs2 kr[4], qtmp[4], vregs[2];
    load_mat_qk(kr[0], krh, 0, ch, r0);
    load_mat_qk(kr[1], krl, 0, ch, r0);
    load_mat_qk(kr[2], kih, 0, ch, r0);
    load_mat_qk(kr[3], kil, 0, ch, r0);
    load_mat_qk(qtmp[0], qrh, i0, ch, r0);
    load_mat_qk(qtmp[1], qrl, i0, ch, r0);
    load_mat_qk(qtmp[2], qih, i0, ch, r0);
    load_mat_qk(qtmp[3], qil, i0, ch, r0);
    #pragma unroll
    for (int m = 0; m < 4; ++m) write_mat(L, KB + m*8192u, qtmp[m], ch, r0);
    #pragma unroll
    for (int m = 0; m < 4; ++m) write_mat(L, KA + m*8192u, kr[m], ch, r0);
    __syncthreads();

    // Q fragments -> registers (64 VGPR)
    s8v qf[4][4];
    #pragma unroll
    for (int m = 0; m < 4; ++m)
        #pragma unroll
        for (int ks = 0; ks < 4; ++ks)
            qf[m][ks] = ldfrag(L, KB + m*8192u, rowA, (u32)(ks*32 + hi*16));

    // ---------------- sweep 1: full QK, per-lane online (m,l) ----------------
    float mx[16], lsum[16];
    #pragma unroll
    for (int r = 0; r < 16; ++r) { mx[r] = 0.f; lsum[r] = 0.f; }

    u32 cur = KA, nxt = KB;
    for (int jt = 0; jt < 32; ++jt) {
        __syncthreads();                                   // K(jt) visible; prev reads done
        if (jt < 31) {
            load_mat_qk(kr[0], krh, (jt+1)*64, ch, r0);
            load_mat_qk(kr[1], krl, (jt+1)*64, ch, r0);
            load_mat_qk(kr[2], kih, (jt+1)*64, ch, r0);
            load_mat_qk(kr[3], kil, (jt+1)*64, ch, r0);
        }
        f32x16 ir, ip, in_;
        #pragma unroll
        for (int r = 0; r < 16; ++r) { ir[r]=0.f; ip[r]=0.f; in_[r]=0.f; }
        #pragma unroll
        for (int ks = 0; ks < 4; ++ks) {
            u32 colb = (u32)(ks*32 + hi*16);
            s8v bRH = ldfrag(L, cur + 0,     rowB, colb);
            s8v bRL = ldfrag(L, cur + 8192,  rowB, colb);
            s8v bIH = ldfrag(L, cur + 16384, rowB, colb);
            s8v bIL = ldfrag(L, cur + 24576, rowB, colb);
            ir = MFMA32(qf[0][ks], bRH, ir); ir = MFMA32(qf[0][ks], bRL, ir); ir = MFMA32(qf[1][ks], bRH, ir);
            ir = MFMA32(qf[2][ks], bIH, ir); ir = MFMA32(qf[2][ks], bIL, ir); ir = MFMA32(qf[3][ks], bIH, ir);
            ip  = MFMA32(qf[0][ks], bIH, ip);  ip  = MFMA32(qf[0][ks], bIL, ip);  ip  = MFMA32(qf[1][ks], bIH, ip);
            in_ = MFMA32(qf[2][ks], bRH, in_); in_ = MFMA32(qf[2][ks], bRL, in_); in_ = MFMA32(qf[3][ks], bRH, in_);
        }
        #pragma unroll
        for (int r = 0; r < 16; ++r) {
            float xr = ir[r], xi = ip[r] - in_[r];
            float s  = fmaf(xr, xr, xi*xi) * 0.125f;
            float mo = mx[r];
            float mn = fmaxf(mo, s);
            lsum[r] = lsum[r]*__expf(mo - mn) + __expf(s - mn);
            mx[r] = mn;
        }
        if (jt < 31) {
            #pragma unroll
            for (int m = 0; m < 4; ++m) write_mat(L, nxt + m*8192u, kr[m], ch, r0);
        }
        u32 t = cur; cur = nxt; nxt = t;
    }

    // lane -> wave-half reduce (over 32 cols)
    #pragma unroll
    for (int off = 1; off < 32; off <<= 1) {
        #pragma unroll
        for (int r = 0; r < 16; ++r) {
            float mo = __shfl_xor(mx[r], off);
            float lo = __shfl_xor(lsum[r], off);
            float mn = fmaxf(mx[r], mo);
            lsum[r] = lsum[r]*__expf(mx[r] - mn) + lo*__expf(mo - mn);
            mx[r] = mn;
        }
    }
    // cross-wc combine via LDS scratch (P region)
    float* sc = (float*)(L + PAC);
    __syncthreads();
    if (l31 == 0) {
        #pragma unroll
        for (int r = 0; r < 16; ++r) {
            u32 row = wr*32 + ROWOF(r,hi);
            sc[wc*64 + row]        = mx[r];
            sc[128 + wc*64 + row]  = lsum[r];
        }
    }
    __syncthreads();
    float mfin[16], linv[16];
    #pragma unroll
    for (int r = 0; r < 16; ++r) {
        u32 row = wr*32 + ROWOF(r,hi);
        float m0 = sc[row], m1 = sc[64 + row];
        float l0 = sc[128 + row], l1 = sc[192 + row];
        float mf = fmaxf(m0, m1);
        mfin[r] = mf;
        linv[r] = 1.0f / (l0*__expf(m0 - mf) + l1*__expf(m1 - mf));
    }

    // ---------------- sweep 2 ----------------
    f32x16 ore, oim;
    #pragma unroll
    for (int r = 0; r < 16; ++r) { ore[r]=0.f; oim[r]=0.f; }

    // prologue: issue K(0), V(0) loads; K(0) -> KA
    load_mat_qk(kr[0], krh, 0, ch, r0);
    load_mat_qk(kr[1], krl, 0, ch, r0);
    load_mat_qk(kr[2], kih, 0, ch, r0);
    load_mat_qk(kr[3], kil, 0, ch, r0);
    load_mat_vt(vregs[0], vtr, 0, ch, r0);
    load_mat_vt(vregs[1], vti, 0, ch, r0);
    #pragma unroll
    for (int m = 0; m < 4; ++m) write_mat(L, KA + m*8192u, kr[m], ch, r0);

    for (int jt = 0; jt < 32; ++jt) {
        const int j0 = jt * 64;
        __syncthreads();                                   // #1: K(jt),V? visible; PV(jt-1) done
        if (jt < 31) {
            load_mat_qk(kr[0], krh, j0 + 64, ch, r0);
            load_mat_qk(kr[1], krl, j0 + 64, ch, r0);
            load_mat_qk(kr[2], kih, j0 + 64, ch, r0);
            load_mat_qk(kr[3], kil, j0 + 64, ch, r0);
        }
        f32x16 ir, ip, in_;
        #pragma unroll
        for (int r = 0; r < 16; ++r) { ir[r]=0.f; ip[r]=0.f; in_[r]=0.f; }
        #pragma unroll
        for (int ks = 0; ks < 4; ++ks) {
            u32 colb = (u32)(ks*32 + hi*16);
            s8v bRH = ldfrag(L, KA + 0,     rowB, colb);
            s8v bRL = ldfrag(L, KA + 8192,  rowB, colb);
            s8v bIH = ldfrag(L, KA + 16384, rowB, colb);
            s8v bIL = ldfrag(L, KA + 24576, rowB, colb);
            ir = MFMA32(qf[0][ks], bRH, ir); ir = MFMA32(qf[0][ks], bRL, ir); ir = MFMA32(qf[1][ks], bRH, ir);
            ir = MFMA32(qf[2][ks], bIH, ir); ir = MFMA32(qf[2][ks], bIL, ir); ir = MFMA32(qf[3][ks], bIH, ir);
            ip  = MFMA32(qf[0][ks], bIH, ip);  ip  = MFMA32(qf[0][ks], bIL, ip);  ip  = MFMA32(qf[1][ks], bIH, ip);
            in_ = MFMA32(qf[2][ks], bRH, in_); in_ = MFMA32(qf[2][ks], bRL, in_); in_ = MFMA32(qf[3][ks], bRH, in_);
        }
        // pointwise: normalized e, attention store, normalized P -> LDS
        float* arow = attnbuf + (size_t)bh*4194304ull + (size_t)i0*2048 + j0 + wc*32 + l31;
        #pragma unroll
        for (int r = 0; r < 16; ++r) {
            float xr = ir[r], xi = ip[r] - in_[r];
            float q  = fmaf(xr, xr, xi*xi);
            float e  = __expf(fmaf(q, 0.125f, -mfin[r])) * linv[r];
            float iv = rsqrtf(q);
            float cc = (q > 0.f) ? xr*iv : 1.0f;
            float ss = (q > 0.f) ? xi*iv : 0.0f;
            u32 rowloc = wr*32 + ROWOF(r,hi);
            arow[(size_t)rowloc*2048] = e;
            u32 colb2 = (wc*32 + l31)*2;
            *(u16*)(L + PAC + rowloc*128u + (colb2 ^ ((rowloc&7u)<<4))) = f2bf(e*cc);
            *(u16*)(L + PAS + rowloc*128u + (colb2 ^ ((rowloc&7u)<<4))) = f2bf(e*ss);
        }
        // V(jt) regs -> LDS (V region free since PV(jt-1) finished before #1)
        write_mat(L, VRo, vregs[0], ch, r0);
        write_mat(L, VIo, vregs[1], ch, r0);
        __syncthreads();                                   // #2: QK reads done; V,P visible
        if (jt < 31) {
            #pragma unroll
            for (int m = 0; m < 4; ++m) write_mat(L, KA + m*8192u, kr[m], ch, r0);
            load_mat_vt(vregs[0], vtr, j0 + 64, ch, r0);
            load_mat_vt(vregs[1], vti, j0 + 64, ch, r0);
        }
        #pragma unroll
        for (int ks = 0; ks < 4; ++ks) {
            u32 colb = (u32)(ks*32 + hi*16);
            s8v aC = ldfrag(L, PAC, rowA, colb);
            s8v aS = ldfrag(L, PAS, rowA, colb);
            s8v vR = ldfrag(L, VRo, rowB, colb);
            s8v vI = ldfrag(L, VIo, rowB, colb);
            s8v vN = vI ^ (short)0x8000;                   // -Vi (sign-bit flip)
            ore = MFMA32(aC, vR, ore); ore = MFMA32(aS, vN, ore);
            oim = MFMA32(aS, vR, oim); oim = MFMA32(aC, vI, oim);
        }
    }

    // ---------------- epilogue: store normalized O splits ----------------
    const int b_ = bh >> 3, h = bh & 7;
    const size_t cb = (size_t)h*64 + wc*32 + l31;
    #pragma unroll
    for (int r = 0; r < 16; ++r) {
        u32 row = wr*32 + ROWOF(r,hi);
        size_t idx = ((size_t)b_*2048 + i0 + row)*512 + cb;
        float vr = ore[r];
        float vi = oim[r];
        u16 hr = f2bf(vr); orh[idx] = hr; orl[idx] = f2bf(vr - bf2f(hr));
        u16 hw = f2bf(vi); oih[idx] = hw; oil[idx] = f2bf(vi - bf2f(hw));
    }
}

// ============================================================
// O projection: out = o @ Wo^T + bo, 3-term split-bf16 MFMA. (unchanged)
// ============================================================
__global__ __launch_bounds__(256, 2)
void oproj_mfma_kernel(const unsigned char* __restrict__ wsb,
                       const float* __restrict__ Wo, const float* __restrict__ bo,
                       float* __restrict__ out)
{
    const int z = blockIdx.z;
    const u16* Ah_g = (const u16*)(wsb + (z ? OIH_OFF : ORH_OFF));
    const u16* Al_g = (const u16*)(wsb + (z ? OIL_OFF : ORL_OFF));
    float* outp = out + (size_t)z * PE_;

    const int m0 = blockIdx.x * 128;
    const int n0 = blockIdx.y * 64;

    __shared__ __align__(16) unsigned char L[49152];
    enum : u32 { AH=0, AL=16384, BH=32768, BL=40960 };

    const int tid  = threadIdx.x;
    const int lane = tid & 63;
    const int wid  = tid >> 6;
    const int wr   = wid >> 1, wc = wid & 1;
    const int l31  = lane & 31;
    const int hi   = lane >> 5;
    const u32 rowA0 = (u32)(wr*64 + l31);
    const u32 rowB  = (u32)(wc*32 + l31);

    f32x16 c0, c1;
    #pragma unroll
    for (int r = 0; r < 16; ++r) { c0[r] = 0.f; c1[r] = 0.f; }

    const int ch = tid & 7, r0 = tid >> 3;

    for (int k0 = 0; k0 < 512; k0 += 64) {
        __syncthreads();
        #pragma unroll
        for (int rr = 0; rr < 4; ++rr) {
            u32 row = (u32)(rr*32 + r0);
            u32 dst = row*128u + (((u32)ch<<4) ^ ((row&7u)<<4));
            us8 vh = *(const us8*)(Ah_g + (size_t)(m0 + row)*512 + k0 + ch*8);
            us8 vl = *(const us8*)(Al_g + (size_t)(m0 + row)*512 + k0 + ch*8);
            *(us8*)(L + AH + dst) = vh;
            *(us8*)(L + AL + dst) = vl;
        }
        #pragma unroll
        for (int rr = 0; rr < 2; ++rr) {
            u32 row = (u32)(rr*32 + r0);
            const float* src = Wo + (size_t)(n0 + row)*512 + k0 + ch*8;
            float4 v0 = *(const float4*)src;
            float4 v1 = *(const float4*)(src + 4);
            float vv[8] = { v0.x,v0.y,v0.z,v0.w, v1.x,v1.y,v1.z,v1.w };
            us8 hv, lv;
            #pragma unroll
            for (int j = 0; j < 8; ++j) {
                u16 hb = f2bf(vv[j]);
                hv[j] = hb;
                lv[j] = f2bf(vv[j] - bf2f(hb));
            }
            u32 dst = row*128u + (((u32)ch<<4) ^ ((row&7u)<<4));
            *(us8*)(L + BH + dst) = hv;
            *(us8*)(L + BL + dst) = lv;
        }
        __syncthreads();

        #pragma unroll
        for (int ks = 0; ks < 4; ++ks) {
            u32 colb = (u32)(ks*32 + hi*16);
            s8v a0h = ldfrag(L, AH, rowA0,      colb);
            s8v a1h = ldfrag(L, AH, rowA0 + 32, colb);
            s8v a0l = ldfrag(L, AL, rowA0,      colb);
            s8v a1l = ldfrag(L, AL, rowA0 + 32, colb);
            s8v bh_ = ldfrag(L, BH, rowB,       colb);
            s8v bl_ = ldfrag(L, BL, rowB,       colb);
            c0 = MFMA32(a0h, bh_, c0); c0 = MFMA32(a0h, bl_, c0); c0 = MFMA32(a0l, bh_, c0);
            c1 = MFMA32(a1h, bh_, c1); c1 = MFMA32(a1h, bl_, c1); c1 = MFMA32(a1l, bh_, c1);
        }
    }

    const int n = n0 + wc*32 + l31;
    const float bvv = bo[n];
    #pragma unroll
    for (int f = 0; f < 2; ++f) {
        const f32x16& c = f ? c1 : c0;
        #pragma unroll
        for (int r = 0; r < 16; ++r) {
            int m = m0 + wr*64 + 32*f + ROWOF(r, hi);
            outp[(size_t)m*512 + n] = c[r] + bvv;
        }
    }
}

// ============================================================
extern "C" void kernel_launch(void* const* d_in, const int* in_sizes, int n_in,
                              void* d_out, int out_size, void* d_ws, size_t ws_size,
                              hipStream_t stream)
{
    const float* wave_real = (const float*)d_in[0];
    const float* wave_imag = (const float*)d_in[1];
    const float* Wq = (const float*)d_in[2]; const float* bq = (const float*)d_in[3];
    const float* Wk = (const float*)d_in[4]; const float* bk = (const float*)d_in[5];
    const float* Wv = (const float*)d_in[6]; const float* bv = (const float*)d_in[7];
    const float* Wo = (const float*)d_in[8]; const float* bo = (const float*)d_in[9];
    float* out = (float*)d_out;
    unsigned char* outb = (unsigned char*)d_out;
    unsigned char* wsb  = (unsigned char*)d_ws;

    float* attnbuf = out + 2*PE_;

    split_prep_kernel<<<dim3(2048, 2), dim3(256), 0, stream>>>(wave_real, wave_imag, outb);

    proj_mfma_kernel<<<dim3(32, 8, 6), dim3(256), 0, stream>>>(
        outb, Wq, Wk, Wv, bq, bk, bv,
        (u16*)wsb, (u16*)(wsb + VT_OFF));

    attn_mfma_kernel<<<dim3(16, 32), dim3(256), 0, stream>>>(
        (const u16*)wsb, (const u16*)(wsb + VT_OFF), attnbuf,
        (u16*)(wsb + ORH_OFF), (u16*)(wsb + ORL_OFF),
        (u16*)(wsb + OIH_OFF), (u16*)(wsb + OIL_OFF));

    oproj_mfma_kernel<<<dim3(32, 8, 2), dim3(256), 0, stream>>>(
        wsb, Wo, bo, out);
}